// Round 1
// baseline (4229.717 us; speedup 1.0000x reference)
//
#include <hip/hip_runtime.h>
#include <hip/hip_bf16.h>
#include <math.h>

typedef __hip_bfloat16 bf16_t;
typedef float f32x4 __attribute__((ext_vector_type(4)));
typedef short short8 __attribute__((ext_vector_type(8)));

#define HIDDEN 3072
#define NH 24
#define HD 128
#define SEQ 2048
#define N1 21504      // 3*HIDDEN + MLP_HIDDEN
#define K2 15360      // HIDDEN + MLP_HIDDEN
#define MODN 9216

static __device__ __forceinline__ bf16_t f2bf(float v){ return __float2bfloat16(v); }

static __device__ __forceinline__ unsigned short f2bfbits(float f){
  unsigned u = __float_as_uint(f);
  unsigned r = (u + 0x7fffu + ((u >> 16) & 1u)) >> 16;
  return (unsigned short)r;
}

static __device__ __forceinline__ float gelu_tanh(float v){
  float u = v * (0.7978845608028654f + 0.03567740813636141f * v * v);
  float e = __expf(2.f * u);
  float th = 1.f - 2.f / (e + 1.f);
  return 0.5f * v * (1.f + th);
}

static __device__ __forceinline__ float wave_sum(float v){
  for (int off = 32; off; off >>= 1) v += __shfl_xor(v, off);
  return v;
}

static __device__ __forceinline__ void gload_lds16(const void* g, void* l){
  __builtin_amdgcn_global_load_lds(
      (const __attribute__((address_space(1))) void*)g,
      (__attribute__((address_space(3))) void*)l, 16, 0, 0);
}

// ---------------- kernel 1: silu(vec) + mod init ----------------
__global__ __launch_bounds__(256) void prep_kernel(const float* __restrict__ vec,
                                                   const float* __restrict__ mod_b,
                                                   float* __restrict__ sv,
                                                   float* __restrict__ mod){
  int i = blockIdx.x * 256 + threadIdx.x;   // 12288 threads
  if (i < HIDDEN){ float v = vec[i]; sv[i] = v / (1.f + __expf(-v)); }
  int j = i - HIDDEN;
  if (j >= 0 && j < MODN) mod[j] = mod_b[j];
}

// ---------------- kernel 2: mod = silu(vec) @ mod_w (+mod_b already) -----
__global__ __launch_bounds__(256) void mod_gemv(const float* __restrict__ sv,
                                                const float* __restrict__ mod_w,
                                                float* __restrict__ mod){
  int n = blockIdx.x * 256 + threadIdx.x;   // gridDim.x = 36
  int k0 = blockIdx.y * 384;                // gridDim.y = 8
  float acc = 0.f;
  for (int k = k0; k < k0 + 384; ++k)
    acc += sv[k] * mod_w[(size_t)k * MODN + n];
  atomicAdd(&mod[n], acc);
}

// ---------------- kernel 3: layernorm + (1+scale)*xhat + shift → bf16 ----
__global__ __launch_bounds__(256) void ln_mod_kernel(const float* __restrict__ x,
                                                     const float* __restrict__ mod,
                                                     bf16_t* __restrict__ xmod){
  const int l = blockIdx.x, t = threadIdx.x;
  const float* xr = x + (size_t)l * HIDDEN;
  float v[12]; float s = 0.f, s2 = 0.f;
  for (int i = 0; i < 12; ++i){ float a = xr[i*256 + t]; v[i] = a; s += a; s2 += a*a; }
  __shared__ float rs[8];
  int wv = t >> 6, ln = t & 63;
  s = wave_sum(s); s2 = wave_sum(s2);
  if (!ln){ rs[wv] = s; rs[4 + wv] = s2; }
  __syncthreads();
  s  = rs[0] + rs[1] + rs[2] + rs[3];
  s2 = rs[4] + rs[5] + rs[6] + rs[7];
  float mean = s * (1.f/3072.f);
  float var  = s2 * (1.f/3072.f) - mean*mean;
  float inv  = rsqrtf(var + 1e-6f);
  bf16_t* orow = xmod + (size_t)l * HIDDEN;
  for (int i = 0; i < 12; ++i){
    int c = i*256 + t;
    float xh = (v[i] - mean) * inv;
    orow[c] = f2bf((1.f + mod[HIDDEN + c]) * xh + mod[c]);
  }
}

// ---------------- kernel 4: fp32 (R x C) -> bf16 transposed (C x R) ------
__global__ __launch_bounds__(256) void transpose_convert(const float* __restrict__ in,
                                                         unsigned short* __restrict__ out,
                                                         int R, int C){
  __shared__ unsigned short tile[64][72];
  const int t = threadIdx.x;
  const int r0 = blockIdx.y * 64, c0 = blockIdx.x * 64;
  for (int p = 0; p < 4; ++p){
    int idx = p*256 + t;
    int rr = idx >> 4, cc = (idx & 15) * 4;
    float4 v = *(const float4*)(in + (size_t)(r0 + rr) * C + c0 + cc);
    tile[rr][cc+0] = f2bfbits(v.x);
    tile[rr][cc+1] = f2bfbits(v.y);
    tile[rr][cc+2] = f2bfbits(v.z);
    tile[rr][cc+3] = f2bfbits(v.w);
  }
  __syncthreads();
  typedef unsigned short ushort8 __attribute__((ext_vector_type(8)));
  for (int p = 0; p < 2; ++p){
    int idx = p*256 + t;
    int cr = idx >> 3, r8 = (idx & 7) * 8;
    ushort8 o;
    for (int i = 0; i < 8; ++i) o[i] = tile[r8 + i][cr];
    *(ushort8*)(out + (size_t)(c0 + cr) * R + r0 + r8) = o;
  }
}

// ---------------- kernel 5/10: 128x128 bf16 GEMM, A[M][K], Bt[N][K] ------
// MODE 0: +b1, split -> qkv bf16 [2048][9216]; gelu -> a2[:,3072:]
// MODE 1: +b2, out = x + gate * val (fp32)
template<int MODE>
__global__ __launch_bounds__(256) void gemm128(const bf16_t* __restrict__ A,
                                               const bf16_t* __restrict__ Bt, int K,
                                               const float* __restrict__ bias,
                                               bf16_t* __restrict__ qkv,
                                               bf16_t* __restrict__ a2,
                                               const float* __restrict__ x,
                                               const float* __restrict__ mod,
                                               float* __restrict__ out){
  __shared__ bf16_t As[128*32];
  __shared__ bf16_t Bs[128*32];
  const int t = threadIdx.x, wv = t >> 6, ln = t & 63;
  const int lane16 = ln & 15, quad = ln >> 4;
  const int m0 = blockIdx.y * 128, n0 = blockIdx.x * 128;
  const int mw = (wv >> 1) * 64, nw = (wv & 1) * 64;

  f32x4 acc[4][4];
  for (int i = 0; i < 4; ++i) for (int j = 0; j < 4; ++j)
    acc[i][j] = (f32x4){0.f,0.f,0.f,0.f};

  const bf16_t* Arow = A  + (size_t)(m0 + wv*16 + (ln>>2)) * K + (ln&3)*8;
  const bf16_t* Brow = Bt + (size_t)(n0 + wv*16 + (ln>>2)) * K + (ln&3)*8;
  char* lA = (char*)As + wv*16*64 + ln*16;
  char* lB = (char*)Bs + wv*16*64 + ln*16;

  for (int k0 = 0; k0 < K; k0 += 32){
    __syncthreads();
    gload_lds16(Arow + k0,          lA);
    gload_lds16(Arow + (size_t)64*K + k0, lA + 4096);
    gload_lds16(Brow + k0,          lB);
    gload_lds16(Brow + (size_t)64*K + k0, lB + 4096);
    __syncthreads();
    short8 af[4], bfr[4];
    const bf16_t* Ab = As + (mw + lane16)*32 + quad*8;
    const bf16_t* Bb = Bs + (nw + lane16)*32 + quad*8;
    for (int i = 0; i < 4; ++i) af[i]  = *(const short8*)(Ab + i*16*32);
    for (int j = 0; j < 4; ++j) bfr[j] = *(const short8*)(Bb + j*16*32);
    for (int i = 0; i < 4; ++i)
      for (int j = 0; j < 4; ++j)
        acc[i][j] = __builtin_amdgcn_mfma_f32_16x16x32_bf16(af[i], bfr[j], acc[i][j], 0, 0, 0);
  }

  for (int i = 0; i < 4; ++i)
    for (int j = 0; j < 4; ++j){
      int row = m0 + mw + i*16 + quad*4;
      int col = n0 + nw + j*16 + lane16;
      float b = bias[col];
      for (int r = 0; r < 4; ++r){
        float val = acc[i][j][r] + b;
        size_t rr = (size_t)(row + r);
        if (MODE == 0){
          if (col < 9216) qkv[rr*9216 + col] = f2bf(val);
          else            a2[rr*15360 + 3072 + (col - 9216)] = f2bf(gelu_tanh(val));
        } else {
          size_t idx = rr*3072 + col;
          out[idx] = x[idx] + mod[6144 + col] * val;
        }
      }
    }
}

// ---------------- kernel 6: q/k rmsnorm + rope -> head-major -------------
static __device__ __forceinline__ void rms_rope_row(const bf16_t* __restrict__ src,
                                                    const float* __restrict__ w,
                                                    const float* __restrict__ pe4,
                                                    float scale,
                                                    bf16_t* __restrict__ dst, int ln){
  unsigned u = *(const unsigned*)(src + 2*ln);
  float v0 = __uint_as_float(u << 16);
  float v1 = __uint_as_float(u & 0xffff0000u);
  float ss = v0*v0 + v1*v1;
  for (int off = 32; off; off >>= 1) ss += __shfl_xor(ss, off);
  float inv = rsqrtf(ss * (1.f/128.f) + 1.1920929e-07f);
  v0 *= inv * w[2*ln]; v1 *= inv * w[2*ln + 1];
  float4 p = *(const float4*)(pe4 + 4*ln);
  float o0 = (p.x*v0 + p.y*v1) * scale;
  float o1 = (p.z*v0 + p.w*v1) * scale;
  unsigned short s0 = f2bfbits(o0), s1 = f2bfbits(o1);
  *(unsigned*)(dst + 2*ln) = (unsigned)s0 | ((unsigned)s1 << 16);
}

__global__ __launch_bounds__(256) void qk_norm_rope(const bf16_t* __restrict__ qkv,
                                                    const float* __restrict__ pe,
                                                    const float* __restrict__ qn_w,
                                                    const float* __restrict__ kn_w,
                                                    bf16_t* __restrict__ qh,
                                                    bf16_t* __restrict__ kh){
  int wid = blockIdx.x * 4 + (threadIdx.x >> 6);  // 0..49151
  int ln = threadIdx.x & 63;
  int head = wid >> 11, l = wid & 2047;
  const bf16_t* base = qkv + (size_t)l * MODN + head * HD;
  const float* pe4 = pe + (size_t)l * 256;
  // q: fold 1/sqrt(128) attention scale
  rms_rope_row(base,        qn_w, pe4, 0.08838834764831845f, qh + ((size_t)head*SEQ + l)*HD, ln);
  rms_rope_row(base + 3072, kn_w, pe4, 1.0f,                 kh + ((size_t)head*SEQ + l)*HD, ln);
}

// ---------------- kernel 7: v transpose -> vt[head][d][l] ---------------
__global__ __launch_bounds__(256) void v_trans(const bf16_t* __restrict__ qkv,
                                               unsigned short* __restrict__ vt){
  __shared__ unsigned short tile[64][72];
  typedef unsigned short ushort8 __attribute__((ext_vector_type(8)));
  const int head = blockIdx.z;
  const int l0 = blockIdx.x * 64, d0 = blockIdx.y * 64;
  const int t = threadIdx.x;
  for (int p = 0; p < 2; ++p){
    int idx = p*256 + t;
    int lr = idx >> 3, d8 = (idx & 7) * 8;
    ushort8 v = *(const ushort8*)((const unsigned short*)qkv +
                 (size_t)(l0 + lr) * MODN + 6144 + head*HD + d0 + d8);
    for (int i = 0; i < 8; ++i) tile[lr][d8 + i] = v[i];
  }
  __syncthreads();
  for (int p = 0; p < 2; ++p){
    int idx = p*256 + t;
    int dr = idx >> 3, l8 = (idx & 7) * 8;
    ushort8 o;
    for (int i = 0; i < 8; ++i) o[i] = tile[l8 + i][dr];
    *(ushort8*)(vt + ((size_t)head*HD + d0 + dr) * SEQ + l0 + l8) = o;
  }
}

// ---------------- kernel 8: flash attention -----------------------------
__global__ __launch_bounds__(256) void attn_kernel(const bf16_t* __restrict__ qh,
                                                   const bf16_t* __restrict__ kh,
                                                   const bf16_t* __restrict__ vt,
                                                   bf16_t* __restrict__ a2){
  __shared__ bf16_t Ks[32*128];   // [key][d]
  __shared__ bf16_t Vs[128*32];   // [d][key]
  __shared__ bf16_t Ps[4*16*32];  // per-wave [qrow][key]
  const int t = threadIdx.x, wv = t >> 6, ln = t & 63;
  const int lane16 = ln & 15, quad = ln >> 4;
  const int head = blockIdx.x >> 5, qblk = blockIdx.x & 31;
  const int q0 = qblk*64 + wv*16;

  short8 qf[4];
  const bf16_t* qrow = qh + ((size_t)head*SEQ + q0 + lane16) * HD;
  for (int s = 0; s < 4; ++s) qf[s] = *(const short8*)(qrow + s*32 + quad*8);

  f32x4 O[8];
  for (int i = 0; i < 8; ++i) O[i] = (f32x4){0.f,0.f,0.f,0.f};
  float m_run[4] = {-INFINITY,-INFINITY,-INFINITY,-INFINITY};
  float l_run[4] = {0.f,0.f,0.f,0.f};

  bf16_t* Pw = Ps + wv*16*32;

  for (int it = 0; it < 64; ++it){
    const int k0 = it * 32;
    __syncthreads();
    // stage K tile (32 keys x 128 d)
    for (int p = 0; p < 2; ++p){
      int krow = p*16 + wv*4 + (ln >> 4);
      gload_lds16(kh + ((size_t)head*SEQ + k0 + krow)*HD + (ln & 15)*8,
                  (char*)Ks + krow*256 + (ln & 15)*16);
    }
    // stage V tile (128 d x 32 keys) from vt[head][d][l]
    for (int p = 0; p < 2; ++p){
      int drow = p*64 + wv*16 + (ln >> 2);
      gload_lds16(vt + ((size_t)head*HD + drow)*SEQ + k0 + (ln & 3)*8,
                  (char*)Vs + drow*64 + (ln & 3)*16);
    }
    __syncthreads();

    // S = Q K^T (two 16-key subtiles)
    f32x4 S[2];
    for (int sn = 0; sn < 2; ++sn){
      f32x4 a = (f32x4){0.f,0.f,0.f,0.f};
      const bf16_t* Kb = Ks + (sn*16 + lane16)*128 + quad*8;
      for (int s = 0; s < 4; ++s){
        short8 kb = *(const short8*)(Kb + s*32);
        a = __builtin_amdgcn_mfma_f32_16x16x32_bf16(qf[s], kb, a, 0, 0, 0);
      }
      S[sn] = a;
    }

    float pv[2][4], alpha[4];
    for (int r = 0; r < 4; ++r){
      float mx = fmaxf(S[0][r], S[1][r]);
      for (int off = 1; off < 16; off <<= 1) mx = fmaxf(mx, __shfl_xor(mx, off));
      float nm = fmaxf(m_run[r], mx);
      alpha[r] = __expf(m_run[r] - nm);
      float p0 = __expf(S[0][r] - nm);
      float p1 = __expf(S[1][r] - nm);
      float rsum = p0 + p1;
      for (int off = 1; off < 16; off <<= 1) rsum += __shfl_xor(rsum, off);
      l_run[r] = l_run[r]*alpha[r] + rsum;
      m_run[r] = nm;
      pv[0][r] = p0; pv[1][r] = p1;
    }
    for (int tt = 0; tt < 8; ++tt)
      for (int r = 0; r < 4; ++r) O[tt][r] *= alpha[r];

    // P -> LDS (C-layout to A-layout transform)
    for (int sn = 0; sn < 2; ++sn)
      for (int r = 0; r < 4; ++r)
        Pw[(quad*4 + r)*32 + sn*16 + lane16] = f2bf(pv[sn][r]);
    __syncthreads();
    short8 pf = *(const short8*)(Pw + lane16*32 + quad*8);
    for (int tt = 0; tt < 8; ++tt){
      short8 vf = *(const short8*)(Vs + (tt*16 + lane16)*32 + quad*8);
      O[tt] = __builtin_amdgcn_mfma_f32_16x16x32_bf16(pf, vf, O[tt], 0, 0, 0);
    }
  }

  for (int tt = 0; tt < 8; ++tt)
    for (int r = 0; r < 4; ++r){
      float o = O[tt][r] / l_run[r];
      int row = q0 + quad*4 + r;
      int col = head*HD + tt*16 + lane16;
      a2[(size_t)row*K2 + col] = f2bf(o);
    }
}

// ---------------- launcher ----------------------------------------------
extern "C" void kernel_launch(void* const* d_in, const int* in_sizes, int n_in,
                              void* d_out, int out_size, void* d_ws, size_t ws_size,
                              hipStream_t stream) {
  const float* x     = (const float*)d_in[0];
  const float* vec   = (const float*)d_in[1];
  const float* pe    = (const float*)d_in[2];
  const float* w1    = (const float*)d_in[3];
  const float* b1    = (const float*)d_in[4];
  const float* w2    = (const float*)d_in[5];
  const float* b2    = (const float*)d_in[6];
  const float* mod_w = (const float*)d_in[7];
  const float* mod_b = (const float*)d_in[8];
  const float* qn_w  = (const float*)d_in[9];
  const float* kn_w  = (const float*)d_in[10];
  float* out = (float*)d_out;
  char* ws = (char*)d_ws;

  float*  sv   = (float*) (ws + 0);
  float*  mod  = (float*) (ws + 12288);
  bf16_t* xmod = (bf16_t*)(ws + 49152);
  bf16_t* w1t  = (bf16_t*)(ws + 12632064);
  bf16_t* w2t  = (bf16_t*)(ws + 144752640);
  bf16_t* qkv  = (bf16_t*)(ws + 239124480);
  bf16_t* a2   = (bf16_t*)(ws + 276873216);
  bf16_t* qh   = (bf16_t*)(ws + 339787776);
  bf16_t* kh   = (bf16_t*)(ws + 352370688);
  bf16_t* vt   = (bf16_t*)(ws + 364953600);
  // total ws use: ~377.6 MB

  prep_kernel<<<48, 256, 0, stream>>>(vec, mod_b, sv, mod);
  mod_gemv<<<dim3(36, 8), 256, 0, stream>>>(sv, mod_w, mod);
  ln_mod_kernel<<<SEQ, 256, 0, stream>>>(x, mod, xmod);
  transpose_convert<<<dim3(336, 48), 256, 0, stream>>>(w1, (unsigned short*)w1t, 3072, N1);
  transpose_convert<<<dim3(48, 240), 256, 0, stream>>>(w2, (unsigned short*)w2t, K2, 3072);
  gemm128<0><<<dim3(168, 16), 256, 0, stream>>>(xmod, w1t, 3072, b1, qkv, a2,
                                                nullptr, nullptr, nullptr);
  qk_norm_rope<<<12288, 256, 0, stream>>>(qkv, pe, qn_w, kn_w, qh, kh);
  v_trans<<<dim3(32, 2, NH), 256, 0, stream>>>(qkv, (unsigned short*)vt);
  attn_kernel<<<dim3(NH*32), 256, 0, stream>>>(qh, kh, vt, a2);
  gemm128<1><<<dim3(24, 16), 256, 0, stream>>>(a2, w2t, K2, b2, nullptr, nullptr,
                                               x, mod, out);
}

// Round 2
// 1553.071 us; speedup vs baseline: 2.7235x; 2.7235x over previous
//
#include <hip/hip_runtime.h>
#include <hip/hip_bf16.h>
#include <math.h>

typedef __hip_bfloat16 bf16_t;
typedef float f32x4 __attribute__((ext_vector_type(4)));
typedef short short8 __attribute__((ext_vector_type(8)));

#define HIDDEN 3072
#define NH 24
#define HD 128
#define SEQ 2048
#define N1 21504      // 3*HIDDEN + MLP_HIDDEN
#define K2 15360      // HIDDEN + MLP_HIDDEN
#define MODN 9216

static __device__ __forceinline__ bf16_t f2bf(float v){ return __float2bfloat16(v); }

static __device__ __forceinline__ unsigned short f2bfbits(float f){
  unsigned u = __float_as_uint(f);
  unsigned r = (u + 0x7fffu + ((u >> 16) & 1u)) >> 16;
  return (unsigned short)r;
}

static __device__ __forceinline__ float gelu_tanh(float v){
  float u = v * (0.7978845608028654f + 0.03567740813636141f * v * v);
  float e = __expf(2.f * u);
  float th = 1.f - 2.f / (e + 1.f);
  return 0.5f * v * (1.f + th);
}

static __device__ __forceinline__ float wave_sum(float v){
  for (int off = 32; off; off >>= 1) v += __shfl_xor(v, off);
  return v;
}

static __device__ __forceinline__ void gload_lds16(const void* g, void* l){
  __builtin_amdgcn_global_load_lds(
      (const __attribute__((address_space(1))) void*)g,
      (__attribute__((address_space(3))) void*)l, 16, 0, 0);
}

// ---------------- kernel 1: silu(vec) + mod init ----------------
__global__ __launch_bounds__(256) void prep_kernel(const float* __restrict__ vec,
                                                   const float* __restrict__ mod_b,
                                                   float* __restrict__ sv,
                                                   float* __restrict__ mod){
  int i = blockIdx.x * 256 + threadIdx.x;   // 12288 threads
  if (i < HIDDEN){ float v = vec[i]; sv[i] = v / (1.f + __expf(-v)); }
  int j = i - HIDDEN;
  if (j >= 0 && j < MODN) mod[j] = mod_b[j];
}

// ---------------- kernel 2: mod = silu(vec) @ mod_w (+mod_b already) -----
__global__ __launch_bounds__(256) void mod_gemv(const float* __restrict__ sv,
                                                const float* __restrict__ mod_w,
                                                float* __restrict__ mod){
  int n = blockIdx.x * 256 + threadIdx.x;   // gridDim.x = 36
  int k0 = blockIdx.y * 384;                // gridDim.y = 8
  float acc = 0.f;
  for (int k = k0; k < k0 + 384; ++k)
    acc += sv[k] * mod_w[(size_t)k * MODN + n];
  atomicAdd(&mod[n], acc);
}

// ---------------- kernel 3: layernorm + (1+scale)*xhat + shift → bf16 ----
__global__ __launch_bounds__(256) void ln_mod_kernel(const float* __restrict__ x,
                                                     const float* __restrict__ mod,
                                                     bf16_t* __restrict__ xmod){
  const int l = blockIdx.x, t = threadIdx.x;
  const float* xr = x + (size_t)l * HIDDEN;
  float v[12]; float s = 0.f, s2 = 0.f;
  #pragma unroll
  for (int i = 0; i < 12; ++i){ float a = xr[i*256 + t]; v[i] = a; s += a; s2 += a*a; }
  __shared__ float rs[8];
  int wv = t >> 6, ln = t & 63;
  s = wave_sum(s); s2 = wave_sum(s2);
  if (!ln){ rs[wv] = s; rs[4 + wv] = s2; }
  __syncthreads();
  s  = rs[0] + rs[1] + rs[2] + rs[3];
  s2 = rs[4] + rs[5] + rs[6] + rs[7];
  float mean = s * (1.f/3072.f);
  float var  = s2 * (1.f/3072.f) - mean*mean;
  float inv  = rsqrtf(var + 1e-6f);
  bf16_t* orow = xmod + (size_t)l * HIDDEN;
  #pragma unroll
  for (int i = 0; i < 12; ++i){
    int c = i*256 + t;
    float xh = (v[i] - mean) * inv;
    orow[c] = f2bf((1.f + mod[HIDDEN + c]) * xh + mod[c]);
  }
}

// ---------------- kernel 4: fp32 (R x C) -> bf16 transposed (C x R) ------
__global__ __launch_bounds__(256) void transpose_convert(const float* __restrict__ in,
                                                         unsigned short* __restrict__ out,
                                                         int R, int C){
  __shared__ unsigned short tile[64][72];
  const int t = threadIdx.x;
  const int r0 = blockIdx.y * 64, c0 = blockIdx.x * 64;
  #pragma unroll
  for (int p = 0; p < 4; ++p){
    int idx = p*256 + t;
    int rr = idx >> 4, cc = (idx & 15) * 4;
    float4 v = *(const float4*)(in + (size_t)(r0 + rr) * C + c0 + cc);
    tile[rr][cc+0] = f2bfbits(v.x);
    tile[rr][cc+1] = f2bfbits(v.y);
    tile[rr][cc+2] = f2bfbits(v.z);
    tile[rr][cc+3] = f2bfbits(v.w);
  }
  __syncthreads();
  typedef unsigned short ushort8 __attribute__((ext_vector_type(8)));
  #pragma unroll
  for (int p = 0; p < 2; ++p){
    int idx = p*256 + t;
    int cr = idx >> 3, r8 = (idx & 7) * 8;
    ushort8 o;
    #pragma unroll
    for (int i = 0; i < 8; ++i) o[i] = tile[r8 + i][cr];
    *(ushort8*)(out + (size_t)(c0 + cr) * R + r0 + r8) = o;
  }
}

// ---------------- kernel 5/10: 128x128 bf16 GEMM, A[M][K], Bt[N][K] ------
// MODE 0: +b1, split -> qkv bf16 [2048][9216]; gelu -> a2[:,3072:]
// MODE 1: +b2, out = x + gate * val (fp32)
// __launch_bounds__(256,2): VGPR budget 256 — without the waves/EU floor the
// backend budgeted 64 VGPRs (LDS-derived 8 waves/EU target) and spilled the
// acc[4][4] array to scratch: 15.6 GB of HBM writes, 3.06 ms (R0 post-mortem).
template<int MODE>
__global__ __launch_bounds__(256, 2) void gemm128(const bf16_t* __restrict__ A,
                                                  const bf16_t* __restrict__ Bt, int K,
                                                  const float* __restrict__ bias,
                                                  bf16_t* __restrict__ qkv,
                                                  bf16_t* __restrict__ a2,
                                                  const float* __restrict__ x,
                                                  const float* __restrict__ mod,
                                                  float* __restrict__ out){
  __shared__ bf16_t As[128*32];
  __shared__ bf16_t Bs[128*32];
  const int t = threadIdx.x, wv = t >> 6, ln = t & 63;
  const int lane16 = ln & 15, quad = ln >> 4;
  const int m0 = blockIdx.y * 128, n0 = blockIdx.x * 128;
  const int mw = (wv >> 1) * 64, nw = (wv & 1) * 64;

  f32x4 acc[4][4];
  #pragma unroll
  for (int i = 0; i < 4; ++i)
    #pragma unroll
    for (int j = 0; j < 4; ++j)
      acc[i][j] = (f32x4){0.f,0.f,0.f,0.f};

  const bf16_t* Arow = A  + (size_t)(m0 + wv*16 + (ln>>2)) * K + (ln&3)*8;
  const bf16_t* Brow = Bt + (size_t)(n0 + wv*16 + (ln>>2)) * K + (ln&3)*8;
  char* lA = (char*)As + wv*16*64 + ln*16;
  char* lB = (char*)Bs + wv*16*64 + ln*16;

  for (int k0 = 0; k0 < K; k0 += 32){
    __syncthreads();
    gload_lds16(Arow + k0,          lA);
    gload_lds16(Arow + (size_t)64*K + k0, lA + 4096);
    gload_lds16(Brow + k0,          lB);
    gload_lds16(Brow + (size_t)64*K + k0, lB + 4096);
    __syncthreads();
    short8 af[4], bfr[4];
    const bf16_t* Ab = As + (mw + lane16)*32 + quad*8;
    const bf16_t* Bb = Bs + (nw + lane16)*32 + quad*8;
    #pragma unroll
    for (int i = 0; i < 4; ++i) af[i]  = *(const short8*)(Ab + i*16*32);
    #pragma unroll
    for (int j = 0; j < 4; ++j) bfr[j] = *(const short8*)(Bb + j*16*32);
    #pragma unroll
    for (int i = 0; i < 4; ++i)
      #pragma unroll
      for (int j = 0; j < 4; ++j)
        acc[i][j] = __builtin_amdgcn_mfma_f32_16x16x32_bf16(af[i], bfr[j], acc[i][j], 0, 0, 0);
  }

  #pragma unroll
  for (int i = 0; i < 4; ++i)
    #pragma unroll
    for (int j = 0; j < 4; ++j){
      int row = m0 + mw + i*16 + quad*4;
      int col = n0 + nw + j*16 + lane16;
      float b = bias[col];
      #pragma unroll
      for (int r = 0; r < 4; ++r){
        float val = acc[i][j][r] + b;
        size_t rr = (size_t)(row + r);
        if (MODE == 0){
          if (col < 9216) qkv[rr*9216 + col] = f2bf(val);
          else            a2[rr*15360 + 3072 + (col - 9216)] = f2bf(gelu_tanh(val));
        } else {
          size_t idx = rr*3072 + col;
          out[idx] = x[idx] + mod[6144 + col] * val;
        }
      }
    }
}

// ---------------- kernel 6: q/k rmsnorm + rope -> head-major -------------
static __device__ __forceinline__ void rms_rope_row(const bf16_t* __restrict__ src,
                                                    const float* __restrict__ w,
                                                    const float* __restrict__ pe4,
                                                    float scale,
                                                    bf16_t* __restrict__ dst, int ln){
  unsigned u = *(const unsigned*)(src + 2*ln);
  float v0 = __uint_as_float(u << 16);
  float v1 = __uint_as_float(u & 0xffff0000u);
  float ss = v0*v0 + v1*v1;
  for (int off = 32; off; off >>= 1) ss += __shfl_xor(ss, off);
  float inv = rsqrtf(ss * (1.f/128.f) + 1.1920929e-07f);
  v0 *= inv * w[2*ln]; v1 *= inv * w[2*ln + 1];
  float4 p = *(const float4*)(pe4 + 4*ln);
  float o0 = (p.x*v0 + p.y*v1) * scale;
  float o1 = (p.z*v0 + p.w*v1) * scale;
  unsigned short s0 = f2bfbits(o0), s1 = f2bfbits(o1);
  *(unsigned*)(dst + 2*ln) = (unsigned)s0 | ((unsigned)s1 << 16);
}

__global__ __launch_bounds__(256) void qk_norm_rope(const bf16_t* __restrict__ qkv,
                                                    const float* __restrict__ pe,
                                                    const float* __restrict__ qn_w,
                                                    const float* __restrict__ kn_w,
                                                    bf16_t* __restrict__ qh,
                                                    bf16_t* __restrict__ kh){
  int wid = blockIdx.x * 4 + (threadIdx.x >> 6);  // 0..49151
  int ln = threadIdx.x & 63;
  int head = wid >> 11, l = wid & 2047;
  const bf16_t* base = qkv + (size_t)l * MODN + head * HD;
  const float* pe4 = pe + (size_t)l * 256;
  // q: fold 1/sqrt(128) attention scale
  rms_rope_row(base,        qn_w, pe4, 0.08838834764831845f, qh + ((size_t)head*SEQ + l)*HD, ln);
  rms_rope_row(base + 3072, kn_w, pe4, 1.0f,                 kh + ((size_t)head*SEQ + l)*HD, ln);
}

// ---------------- kernel 7: v transpose -> vt[head][d][l] ---------------
__global__ __launch_bounds__(256) void v_trans(const bf16_t* __restrict__ qkv,
                                               unsigned short* __restrict__ vt){
  __shared__ unsigned short tile[64][72];
  typedef unsigned short ushort8 __attribute__((ext_vector_type(8)));
  const int head = blockIdx.z;
  const int l0 = blockIdx.x * 64, d0 = blockIdx.y * 64;
  const int t = threadIdx.x;
  #pragma unroll
  for (int p = 0; p < 2; ++p){
    int idx = p*256 + t;
    int lr = idx >> 3, d8 = (idx & 7) * 8;
    ushort8 v = *(const ushort8*)((const unsigned short*)qkv +
                 (size_t)(l0 + lr) * MODN + 6144 + head*HD + d0 + d8);
    #pragma unroll
    for (int i = 0; i < 8; ++i) tile[lr][d8 + i] = v[i];
  }
  __syncthreads();
  #pragma unroll
  for (int p = 0; p < 2; ++p){
    int idx = p*256 + t;
    int dr = idx >> 3, l8 = (idx & 7) * 8;
    ushort8 o;
    #pragma unroll
    for (int i = 0; i < 8; ++i) o[i] = tile[l8 + i][dr];
    *(ushort8*)(vt + ((size_t)head*HD + d0 + dr) * SEQ + l0 + l8) = o;
  }
}

// ---------------- kernel 8: flash attention -----------------------------
__global__ __launch_bounds__(256, 2) void attn_kernel(const bf16_t* __restrict__ qh,
                                                      const bf16_t* __restrict__ kh,
                                                      const bf16_t* __restrict__ vt,
                                                      bf16_t* __restrict__ a2){
  __shared__ bf16_t Ks[32*128];   // [key][d]
  __shared__ bf16_t Vs[128*32];   // [d][key]
  __shared__ bf16_t Ps[4*16*32];  // per-wave [qrow][key]
  const int t = threadIdx.x, wv = t >> 6, ln = t & 63;
  const int lane16 = ln & 15, quad = ln >> 4;
  const int head = blockIdx.x >> 5, qblk = blockIdx.x & 31;
  const int q0 = qblk*64 + wv*16;

  short8 qf[4];
  const bf16_t* qrow = qh + ((size_t)head*SEQ + q0 + lane16) * HD;
  #pragma unroll
  for (int s = 0; s < 4; ++s) qf[s] = *(const short8*)(qrow + s*32 + quad*8);

  f32x4 O[8];
  #pragma unroll
  for (int i = 0; i < 8; ++i) O[i] = (f32x4){0.f,0.f,0.f,0.f};
  float m_run[4] = {-INFINITY,-INFINITY,-INFINITY,-INFINITY};
  float l_run[4] = {0.f,0.f,0.f,0.f};

  bf16_t* Pw = Ps + wv*16*32;

  for (int it = 0; it < 64; ++it){
    const int k0 = it * 32;
    __syncthreads();
    // stage K tile (32 keys x 128 d)
    #pragma unroll
    for (int p = 0; p < 2; ++p){
      int krow = p*16 + wv*4 + (ln >> 4);
      gload_lds16(kh + ((size_t)head*SEQ + k0 + krow)*HD + (ln & 15)*8,
                  (char*)Ks + krow*256 + (ln & 15)*16);
    }
    // stage V tile (128 d x 32 keys) from vt[head][d][l]
    #pragma unroll
    for (int p = 0; p < 2; ++p){
      int drow = p*64 + wv*16 + (ln >> 2);
      gload_lds16(vt + ((size_t)head*HD + drow)*SEQ + k0 + (ln & 3)*8,
                  (char*)Vs + drow*64 + (ln & 3)*16);
    }
    __syncthreads();

    // S = Q K^T (two 16-key subtiles)
    f32x4 S[2];
    #pragma unroll
    for (int sn = 0; sn < 2; ++sn){
      f32x4 a = (f32x4){0.f,0.f,0.f,0.f};
      const bf16_t* Kb = Ks + (sn*16 + lane16)*128 + quad*8;
      #pragma unroll
      for (int s = 0; s < 4; ++s){
        short8 kb = *(const short8*)(Kb + s*32);
        a = __builtin_amdgcn_mfma_f32_16x16x32_bf16(qf[s], kb, a, 0, 0, 0);
      }
      S[sn] = a;
    }

    float pv[2][4], alpha[4];
    #pragma unroll
    for (int r = 0; r < 4; ++r){
      float mx = fmaxf(S[0][r], S[1][r]);
      #pragma unroll
      for (int off = 1; off < 16; off <<= 1) mx = fmaxf(mx, __shfl_xor(mx, off));
      float nm = fmaxf(m_run[r], mx);
      alpha[r] = __expf(m_run[r] - nm);
      float p0 = __expf(S[0][r] - nm);
      float p1 = __expf(S[1][r] - nm);
      float rsum = p0 + p1;
      #pragma unroll
      for (int off = 1; off < 16; off <<= 1) rsum += __shfl_xor(rsum, off);
      l_run[r] = l_run[r]*alpha[r] + rsum;
      m_run[r] = nm;
      pv[0][r] = p0; pv[1][r] = p1;
    }
    #pragma unroll
    for (int tt = 0; tt < 8; ++tt)
      #pragma unroll
      for (int r = 0; r < 4; ++r) O[tt][r] *= alpha[r];

    // P -> LDS (C-layout to A-layout transform)
    #pragma unroll
    for (int sn = 0; sn < 2; ++sn)
      #pragma unroll
      for (int r = 0; r < 4; ++r)
        Pw[(quad*4 + r)*32 + sn*16 + lane16] = f2bf(pv[sn][r]);
    __syncthreads();
    short8 pf = *(const short8*)(Pw + lane16*32 + quad*8);
    #pragma unroll
    for (int tt = 0; tt < 8; ++tt){
      short8 vf = *(const short8*)(Vs + (tt*16 + lane16)*32 + quad*8);
      O[tt] = __builtin_amdgcn_mfma_f32_16x16x32_bf16(pf, vf, O[tt], 0, 0, 0);
    }
  }

  #pragma unroll
  for (int tt = 0; tt < 8; ++tt)
    #pragma unroll
    for (int r = 0; r < 4; ++r){
      float o = O[tt][r] / l_run[r];
      int row = q0 + quad*4 + r;
      int col = head*HD + tt*16 + lane16;
      a2[(size_t)row*K2 + col] = f2bf(o);
    }
}

// ---------------- launcher ----------------------------------------------
extern "C" void kernel_launch(void* const* d_in, const int* in_sizes, int n_in,
                              void* d_out, int out_size, void* d_ws, size_t ws_size,
                              hipStream_t stream) {
  const float* x     = (const float*)d_in[0];
  const float* vec   = (const float*)d_in[1];
  const float* pe    = (const float*)d_in[2];
  const float* w1    = (const float*)d_in[3];
  const float* b1    = (const float*)d_in[4];
  const float* w2    = (const float*)d_in[5];
  const float* b2    = (const float*)d_in[6];
  const float* mod_w = (const float*)d_in[7];
  const float* mod_b = (const float*)d_in[8];
  const float* qn_w  = (const float*)d_in[9];
  const float* kn_w  = (const float*)d_in[10];
  float* out = (float*)d_out;
  char* ws = (char*)d_ws;

  float*  sv   = (float*) (ws + 0);
  float*  mod  = (float*) (ws + 12288);
  bf16_t* xmod = (bf16_t*)(ws + 49152);
  bf16_t* w1t  = (bf16_t*)(ws + 12632064);
  bf16_t* w2t  = (bf16_t*)(ws + 144752640);
  bf16_t* qkv  = (bf16_t*)(ws + 239124480);
  bf16_t* a2   = (bf16_t*)(ws + 276873216);
  bf16_t* qh   = (bf16_t*)(ws + 339787776);
  bf16_t* kh   = (bf16_t*)(ws + 352370688);
  bf16_t* vt   = (bf16_t*)(ws + 364953600);
  // total ws use: ~377.6 MB

  prep_kernel<<<48, 256, 0, stream>>>(vec, mod_b, sv, mod);
  mod_gemv<<<dim3(36, 8), 256, 0, stream>>>(sv, mod_w, mod);
  ln_mod_kernel<<<SEQ, 256, 0, stream>>>(x, mod, xmod);
  transpose_convert<<<dim3(336, 48), 256, 0, stream>>>(w1, (unsigned short*)w1t, 3072, N1);
  transpose_convert<<<dim3(48, 240), 256, 0, stream>>>(w2, (unsigned short*)w2t, K2, 3072);
  gemm128<0><<<dim3(168, 16), 256, 0, stream>>>(xmod, w1t, 3072, b1, qkv, a2,
                                                nullptr, nullptr, nullptr);
  qk_norm_rope<<<12288, 256, 0, stream>>>(qkv, pe, qn_w, kn_w, qh, kh);
  v_trans<<<dim3(32, 2, NH), 256, 0, stream>>>(qkv, (unsigned short*)vt);
  attn_kernel<<<dim3(NH*32), 256, 0, stream>>>(qh, kh, vt, a2);
  gemm128<1><<<dim3(24, 16), 256, 0, stream>>>(a2, w2t, K2, b2, nullptr, nullptr,
                                               x, mod, out);
}